// Round 1
// 7855.537 us; speedup vs baseline: 2.0832x; 2.0832x over previous
//
#include <hip/hip_runtime.h>
#include <hip/hip_bf16.h>

#define TN 2048      // B*T tokens
#define TT 1024      // T
#define DM 768       // D
#define NH 12        // heads
#define HDM 64       // head dim
#define NE 4         // experts
#define NL 2         // layers
#define NV 50257     // vocab
#define FF 3072      // 4*D

// ---------------- embedding: x = wte[idx] + wpe[t] ----------------
__global__ __launch_bounds__(256) void embed_kernel(
    const int* __restrict__ idx, const float* __restrict__ wte,
    const float* __restrict__ wpe, float* __restrict__ X) {
  int n = blockIdx.x;            // token
  int t = n % TT;
  int tok = idx[n];
  const float* we = wte + (size_t)tok * DM;
  const float* pe = wpe + (size_t)t * DM;
  float* xr = X + (size_t)n * DM;
  for (int d = threadIdx.x; d < DM; d += 256)
    xr[d] = we[d] + pe[d];
}

// ---------------- LayerNorm ----------------
__global__ __launch_bounds__(256) void ln_kernel(
    const float* __restrict__ X, float* __restrict__ Y,
    const float* __restrict__ g, const float* __restrict__ b) {
  int row = blockIdx.x;
  const float* x = X + (size_t)row * DM;
  float* y = Y + (size_t)row * DM;
  float s = 0.f, ss = 0.f;
  for (int d = threadIdx.x; d < DM; d += 256) {
    float v = x[d]; s += v; ss += v * v;
  }
#pragma unroll
  for (int off = 32; off; off >>= 1) {
    s  += __shfl_xor(s, off);
    ss += __shfl_xor(ss, off);
  }
  __shared__ float sb[2][4];
  int w = threadIdx.x >> 6;
  if ((threadIdx.x & 63) == 0) { sb[0][w] = s; sb[1][w] = ss; }
  __syncthreads();
  s  = sb[0][0] + sb[0][1] + sb[0][2] + sb[0][3];
  ss = sb[1][0] + sb[1][1] + sb[1][2] + sb[1][3];
  float mean = s * (1.f / DM);
  float var = ss * (1.f / DM) - mean * mean;
  float rstd = rsqrtf(var + 1e-5f);
  for (int d = threadIdx.x; d < DM; d += 256)
    y[d] = (x[d] - mean) * rstd * g[d] + b[d];
}

// ---------------- gating: top-2 over E=4, softmax, coef ----------------
__global__ __launch_bounds__(64) void gate_kernel(
    const float* __restrict__ Xln, const float* __restrict__ gw,
    const float* __restrict__ nw, const float* __restrict__ noise,
    float* __restrict__ coef) {
  int n = blockIdx.x;
  const float* x = Xln + (size_t)n * DM;
  float ag[NE] = {0.f, 0.f, 0.f, 0.f};
  float an[NE] = {0.f, 0.f, 0.f, 0.f};
  for (int d = threadIdx.x; d < DM; d += 64) {
    float xv = x[d];
#pragma unroll
    for (int e = 0; e < NE; e++) {
      ag[e] += xv * gw[d * NE + e];
      an[e] += xv * nw[d * NE + e];
    }
  }
#pragma unroll
  for (int e = 0; e < NE; e++) {
#pragma unroll
    for (int off = 32; off; off >>= 1) {
      ag[e] += __shfl_xor(ag[e], off);
      an[e] += __shfl_xor(an[e], off);
    }
  }
  float lg[NE];
#pragma unroll
  for (int e = 0; e < NE; e++) {
    float s = an[e];
    float sp = fmaxf(s, 0.f) + log1pf(expf(-fabsf(s)));  // stable softplus
    lg[e] = ag[e] + noise[(size_t)n * NE + e] * sp;
  }
  // top-2, first-index tie-break (matches jax.lax.top_k)
  int i0 = 0; float m0 = lg[0];
#pragma unroll
  for (int e = 1; e < NE; e++) if (lg[e] > m0) { m0 = lg[e]; i0 = e; }
  int i1 = -1; float m1 = -1e30f;
#pragma unroll
  for (int e = 0; e < NE; e++) if (e != i0 && lg[e] > m1) { m1 = lg[e]; i1 = e; }
  float z = expf(m1 - m0);
  float inv = 1.f / (1.f + z);
  float w0 = inv, w1 = z * inv;
  if (threadIdx.x < NE) {
    int e = threadIdx.x;
    float c = (e == i0) ? w0 : ((e == i1) ? w1 : 0.f);
    coef[(size_t)n * NE + e] = c;
  }
}

// ---------------- flash-tile attention ----------------
// block = 256 threads = 4 waves; each wave owns 2 query rows (8 rows/block,
// consecutive t), sharing a 64-key K tile + transposed V tile in LDS.
// Per 64-key tile: lane j computes s_j via float4 dots (LDS), ONE max-reduce +
// ONE exp per row per tile (vs per-key before), PV via float4 reads of Vt rows.
#define QR 8     // query rows per block
#define JT 64    // key tile

__global__ __launch_bounds__(256) void attn_kernel(
    const float* __restrict__ Q, const float* __restrict__ Kb,
    const float* __restrict__ Vb, float* __restrict__ O) {
  __shared__ float Ks[JT][HDM + 4];   // [key j][d]   row stride 68 floats (16B-aligned rows)
  __shared__ float Vt[HDM][JT + 4];   // [d][key j]   transposed for float4 PV reads
  __shared__ float qs[QR][HDM];
  __shared__ float ps[QR][JT];
  int tid = threadIdx.x;
  int wave = tid >> 6, lane = tid & 63;
  const int ngrp = TT / QR;                 // 128
  int grp = blockIdx.x;
  int t0 = (grp % ngrp) * QR;
  int h = (grp / ngrp) % NH;
  int b = grp / (ngrp * NH);
  int tA = t0 + 2 * wave, tB = tA + 1;
  size_t baseA = ((size_t)(b * TT + tA)) * DM + h * HDM;
  size_t baseB = baseA + DM;
  qs[2 * wave][lane]     = Q[baseA + lane] * 0.125f;   // 1/sqrt(64)
  qs[2 * wave + 1][lane] = Q[baseB + lane] * 0.125f;
  float mA = -1e30f, mB = -1e30f, lA = 0.f, lB = 0.f, oA = 0.f, oB = 0.f;
  int r  = tid >> 2;           // key row 0..63 for staging
  int c4 = (tid & 3) << 4;     // 0,16,32,48
  int tmax = t0 + QR - 1;
  for (int j0 = 0; j0 <= tmax; j0 += JT) {
    __syncthreads();   // prior-iter LDS reads done (also covers qs on iter 0)
    {
      size_t kb = ((size_t)(b * TT + j0 + r)) * DM + h * HDM + c4;
      const float* kp = Kb + kb;
      const float* vp = Vb + kb;
      float4 k0 = *(const float4*)(kp + 0);
      float4 k1 = *(const float4*)(kp + 4);
      float4 k2 = *(const float4*)(kp + 8);
      float4 k3 = *(const float4*)(kp + 12);
      *(float4*)&Ks[r][c4 + 0]  = k0;
      *(float4*)&Ks[r][c4 + 4]  = k1;
      *(float4*)&Ks[r][c4 + 8]  = k2;
      *(float4*)&Ks[r][c4 + 12] = k3;
      float4 v0 = *(const float4*)(vp + 0);
      float4 v1 = *(const float4*)(vp + 4);
      float4 v2 = *(const float4*)(vp + 8);
      float4 v3 = *(const float4*)(vp + 12);
      Vt[c4 + 0][r]  = v0.x; Vt[c4 + 1][r]  = v0.y; Vt[c4 + 2][r]  = v0.z; Vt[c4 + 3][r]  = v0.w;
      Vt[c4 + 4][r]  = v1.x; Vt[c4 + 5][r]  = v1.y; Vt[c4 + 6][r]  = v1.z; Vt[c4 + 7][r]  = v1.w;
      Vt[c4 + 8][r]  = v2.x; Vt[c4 + 9][r]  = v2.y; Vt[c4 + 10][r] = v2.z; Vt[c4 + 11][r] = v2.w;
      Vt[c4 + 12][r] = v3.x; Vt[c4 + 13][r] = v3.y; Vt[c4 + 14][r] = v3.z; Vt[c4 + 15][r] = v3.w;
    }
    __syncthreads();
    // ---- scores: lane = key j within tile ----
    float sA = 0.f, sB = 0.f;
    const float4* kr = (const float4*)&Ks[lane][0];
    const float4* qa = (const float4*)&qs[2 * wave][0];
    const float4* qb = (const float4*)&qs[2 * wave + 1][0];
#pragma unroll
    for (int i = 0; i < HDM / 4; i++) {
      float4 k4 = kr[i], a4 = qa[i], b4 = qb[i];
      sA += a4.x * k4.x + a4.y * k4.y + a4.z * k4.z + a4.w * k4.w;
      sB += b4.x * k4.x + b4.y * k4.y + b4.z * k4.z + b4.w * k4.w;
    }
    int gj = j0 + lane;
    sA = (gj <= tA) ? sA : -1e30f;
    sB = (gj <= tB) ? sB : -1e30f;
    float mtA = sA, mtB = sB;
#pragma unroll
    for (int off = 32; off; off >>= 1) {
      mtA = fmaxf(mtA, __shfl_xor(mtA, off));
      mtB = fmaxf(mtB, __shfl_xor(mtB, off));
    }
    float mnA = fmaxf(mA, mtA), mnB = fmaxf(mB, mtB);
    float pA = expf(sA - mnA),  pB = expf(sB - mnB);
    float fA = expf(mA - mnA),  fB = expf(mB - mnB);
    float lsA = pA, lsB = pB;
#pragma unroll
    for (int off = 32; off; off >>= 1) {
      lsA += __shfl_xor(lsA, off);
      lsB += __shfl_xor(lsB, off);
    }
    lA = lA * fA + lsA;  lB = lB * fB + lsB;
    mA = mnA;  mB = mnB;
    ps[2 * wave][lane]     = pA;
    ps[2 * wave + 1][lane] = pB;
    oA *= fA;  oB *= fB;
    __syncthreads();
    // ---- PV: lane = output dim d; Vt row is contiguous over j ----
    const float4* vr = (const float4*)&Vt[lane][0];
    const float4* pa = (const float4*)&ps[2 * wave][0];
    const float4* pb = (const float4*)&ps[2 * wave + 1][0];
#pragma unroll
    for (int i = 0; i < JT / 4; i++) {
      float4 v4 = vr[i], a4 = pa[i], b4 = pb[i];
      oA += a4.x * v4.x + a4.y * v4.y + a4.z * v4.z + a4.w * v4.w;
      oB += b4.x * v4.x + b4.y * v4.y + b4.z * v4.z + b4.w * v4.w;
    }
  }
  O[baseA + lane] = oA / lA;
  O[baseB + lane] = oB / lB;
}

// ---------------- residual add ----------------
__global__ __launch_bounds__(256) void add_kernel(
    float* __restrict__ X, const float* __restrict__ Y, int n) {
  int i = blockIdx.x * 256 + threadIdx.x;
  if (i < n) X[i] += Y[i];
}

// ---------------- generic tiled GEMM (all fp32) ----------------
#define BM 64
#define BN 64
#define BK 16
#define PAD 4

static __device__ __forceinline__ float geluf(float v) {
  const float c = 0.7978845608028654f;  // sqrt(2/pi)
  float t = tanhf(c * (v + 0.044715f * v * v * v));
  return 0.5f * v * (1.f + t);
}

__global__ __launch_bounds__(256) void gemm_kernel(
    const float* __restrict__ A, const float* __restrict__ B, float* __restrict__ C,
    int M, int N, int K, int transB,
    const float* __restrict__ bias, const float* __restrict__ rowscale, int rs_stride,
    int accumulate, int act) {
  __shared__ float As[BK][BM + PAD];
  __shared__ float Bs[BK][BN + PAD];
  int tid = threadIdx.x;
  int bm = blockIdx.y * BM;
  int bn = blockIdx.x * BN;
  int tx = tid & 15, ty = tid >> 4;
  int m0 = ty * 4, n0 = tx * 4;
  float acc[4][4] = {};

  for (int k0 = 0; k0 < K; k0 += BK) {
#pragma unroll
    for (int i = 0; i < 4; i++) {          // A tile: 64 rows x 16 k
      int e = tid + i * 256;
      int m = e >> 4, kk = e & 15;
      int gm = bm + m;
      float v = 0.f;
      if (gm < M) v = A[(size_t)gm * K + k0 + kk];
      As[kk][m] = v;
    }
    if (!transB) {
#pragma unroll
      for (int i = 0; i < 4; i++) {        // B tile: 16 k x 64 n
        int e = tid + i * 256;
        int kk = e >> 6, n = e & 63;
        int gn = bn + n;
        float v = 0.f;
        if (gn < N) v = B[(size_t)(k0 + kk) * N + gn];
        Bs[kk][n] = v;
      }
    } else {
#pragma unroll
      for (int i = 0; i < 4; i++) {
        int e = tid + i * 256;
        int n = e >> 4, kk = e & 15;
        int gn = bn + n;
        float v = 0.f;
        if (gn < N) v = B[(size_t)gn * K + k0 + kk];
        Bs[kk][n] = v;
      }
    }
    __syncthreads();
#pragma unroll
    for (int kk = 0; kk < BK; kk++) {
      float4 av = *(const float4*)&As[kk][m0];
      float4 bv = *(const float4*)&Bs[kk][n0];
      float a[4] = {av.x, av.y, av.z, av.w};
      float bb[4] = {bv.x, bv.y, bv.z, bv.w};
#pragma unroll
      for (int i = 0; i < 4; i++)
#pragma unroll
        for (int j = 0; j < 4; j++)
          acc[i][j] += a[i] * bb[j];
    }
    __syncthreads();
  }

#pragma unroll
  for (int i = 0; i < 4; i++) {
    int gm = bm + m0 + i;
    if (gm >= M) continue;
    float rs = rowscale ? rowscale[(size_t)gm * rs_stride] : 1.f;
#pragma unroll
    for (int j = 0; j < 4; j++) {
      int gn = bn + n0 + j;
      if (gn >= N) continue;
      float v = acc[i][j];
      if (bias) v += bias[gn];
      if (act == 1) v = geluf(v);
      v *= rs;
      size_t ci = (size_t)gm * N + gn;
      if (accumulate) C[ci] += v;
      else            C[ci] = v;
    }
  }
}

// ---------------- 128x128 / 8x8 GEMM, B transposed (lm_head) ----------------
// C[M,N] = A[M,K] @ B[N,K]^T ; fp32, no epilogue.
#define GBM 128
#define GBN 128
#define GBK 16

__global__ __launch_bounds__(256) void gemm128_nt_kernel(
    const float* __restrict__ A, const float* __restrict__ B, float* __restrict__ C,
    int M, int N, int K) {
  __shared__ float As[GBK][GBM + 4];   // row stride 132 floats (16B-aligned rows)
  __shared__ float Bs[GBK][GBN + 4];
  int tid = threadIdx.x;
  int bm = blockIdx.y * GBM;
  int bn = blockIdx.x * GBN;
  int tx = tid & 15, ty = tid >> 4;
  int m0 = ty * 8, n0 = tx * 8;
  float acc[8][8] = {};
  for (int k0 = 0; k0 < K; k0 += GBK) {
#pragma unroll
    for (int i = 0; i < 2; i++) {
      int e = tid + i * 256;
      int r  = e >> 2;            // 0..127
      int q4 = (e & 3) * 4;       // 0,4,8,12
      int gm = bm + r;
      float4 av = make_float4(0.f, 0.f, 0.f, 0.f);
      if (gm < M) av = *(const float4*)&A[(size_t)gm * K + k0 + q4];
      As[q4 + 0][r] = av.x; As[q4 + 1][r] = av.y;
      As[q4 + 2][r] = av.z; As[q4 + 3][r] = av.w;
      int gn = bn + r;
      float4 bv = make_float4(0.f, 0.f, 0.f, 0.f);
      if (gn < N) bv = *(const float4*)&B[(size_t)gn * K + k0 + q4];
      Bs[q4 + 0][r] = bv.x; Bs[q4 + 1][r] = bv.y;
      Bs[q4 + 2][r] = bv.z; Bs[q4 + 3][r] = bv.w;
    }
    __syncthreads();
#pragma unroll
    for (int kk = 0; kk < GBK; kk++) {
      float4 a0 = *(const float4*)&As[kk][m0];
      float4 a1 = *(const float4*)&As[kk][m0 + 4];
      float4 b0 = *(const float4*)&Bs[kk][n0];
      float4 b1 = *(const float4*)&Bs[kk][n0 + 4];
      float a[8]  = {a0.x, a0.y, a0.z, a0.w, a1.x, a1.y, a1.z, a1.w};
      float bb[8] = {b0.x, b0.y, b0.z, b0.w, b1.x, b1.y, b1.z, b1.w};
#pragma unroll
      for (int i = 0; i < 8; i++)
#pragma unroll
        for (int j = 0; j < 8; j++)
          acc[i][j] += a[i] * bb[j];
    }
    __syncthreads();
  }
#pragma unroll
  for (int i = 0; i < 8; i++) {
    int gm = bm + m0 + i;
    if (gm >= M) continue;
    float* crow = C + (size_t)gm * N;
#pragma unroll
    for (int j = 0; j < 8; j++) {
      int gn = bn + n0 + j;
      if (gn < N) crow[gn] = acc[i][j];
    }
  }
}

// ---------------- launch ----------------
extern "C" void kernel_launch(void* const* d_in, const int* in_sizes, int n_in,
                              void* d_out, int out_size, void* d_ws, size_t ws_size,
                              hipStream_t stream) {
  const int*   idx   = (const int*)d_in[0];
  const float* wte   = (const float*)d_in[1];
  const float* wpe   = (const float*)d_in[2];
  const float* ln1_g = (const float*)d_in[3];
  const float* ln1_b = (const float*)d_in[4];
  const float* ln2_g = (const float*)d_in[5];
  const float* ln2_b = (const float*)d_in[6];
  const float* lnf_g = (const float*)d_in[7];
  const float* lnf_b = (const float*)d_in[8];
  const float* Wk    = (const float*)d_in[9];
  const float* Wv    = (const float*)d_in[10];
  const float* Wq    = (const float*)d_in[11];
  const float* Wo    = (const float*)d_in[12];
  const float* gw    = (const float*)d_in[13];
  const float* nw    = (const float*)d_in[14];
  const float* fcw   = (const float*)d_in[15];
  const float* fcb   = (const float*)d_in[16];
  const float* pjw   = (const float*)d_in[17];
  const float* pjb   = (const float*)d_in[18];
  const float* noise = (const float*)d_in[19];

  const size_t ND = (size_t)TN * DM;
  float* x    = (float*)d_ws;
  float* xln  = x + ND;
  float* kbuf = xln + ND;
  float* vbuf = kbuf + ND;
  float* qbuf = vbuf + ND;
  float* obuf = qbuf + ND;
  float* moab = obuf + ND;
  float* hbuf = moab + ND;                 // TN*FF fp32
  float* coef = hbuf + (size_t)TN * FF;    // TN*NE fp32

  embed_kernel<<<TN, 256, 0, stream>>>(idx, wte, wpe, x);

  dim3 gD(DM / BN, TN / BM);
  dim3 gF(FF / BN, TN / BM);
  const int attn_blocks = 2 * NH * (TT / QR);   // B*H*T/8 = 3072

  for (int l = 0; l < NL; l++) {
    ln_kernel<<<TN, 256, 0, stream>>>(x, xln, ln1_g + l * DM, ln1_b + l * DM);
    gate_kernel<<<TN, 64, 0, stream>>>(xln, gw + (size_t)l * DM * NE,
                                       nw + (size_t)l * DM * NE,
                                       noise + (size_t)l * TN * NE, coef);
    gemm_kernel<<<gD, 256, 0, stream>>>(xln, Wk + (size_t)l * DM * DM, kbuf,
                                        TN, DM, DM, 0, nullptr, nullptr, 0, 0, 0);
    gemm_kernel<<<gD, 256, 0, stream>>>(xln, Wv + (size_t)l * DM * DM, vbuf,
                                        TN, DM, DM, 0, nullptr, nullptr, 0, 0, 0);
    for (int e = 0; e < NE; e++) {
      gemm_kernel<<<gD, 256, 0, stream>>>(xln, Wq + ((size_t)l * NE + e) * DM * DM, qbuf,
                                          TN, DM, DM, 0, nullptr, nullptr, 0, 0, 0);
      attn_kernel<<<attn_blocks, 256, 0, stream>>>(qbuf, kbuf, vbuf, obuf);
      gemm_kernel<<<gD, 256, 0, stream>>>(obuf, Wo + ((size_t)l * NE + e) * DM * DM, moab,
                                          TN, DM, DM, 0, nullptr, coef + e, NE,
                                          (e > 0) ? 1 : 0, 0);
    }
    add_kernel<<<(int)(ND / 256), 256, 0, stream>>>(x, moab, (int)ND);
    ln_kernel<<<TN, 256, 0, stream>>>(x, xln, ln2_g + l * DM, ln2_b + l * DM);
    gemm_kernel<<<gF, 256, 0, stream>>>(xln, fcw + (size_t)l * DM * FF, hbuf,
                                        TN, FF, DM, 0, fcb + (size_t)l * FF,
                                        nullptr, 0, 0, 1);
    gemm_kernel<<<gD, 256, 0, stream>>>(hbuf, pjw + (size_t)l * FF * DM, x,
                                        TN, DM, FF, 0, pjb + (size_t)l * DM,
                                        nullptr, 0, 1, 0);
  }

  ln_kernel<<<TN, 256, 0, stream>>>(x, xln, lnf_g, lnf_b);
  dim3 gV((NV + GBN - 1) / GBN, TN / GBM);
  gemm128_nt_kernel<<<gV, 256, 0, stream>>>(xln, wte, (float*)d_out, TN, NV, DM);
}